// Round 5
// 8896.082 us; speedup vs baseline: 1.1838x; 1.1838x over previous
//
#include <hip/hip_runtime.h>
#include <stdint.h>

namespace {

constexpr int H = 1024;
constexpr int V = 32000;
constexpr int B = 32;
constexpr int T = 64;
constexpr int NPART = V / 64;    // 500 argmax partials per batch row (one per 64-v tile)
constexpr long long OUT_LOGITS = (long long)B * T * V;  // 65,536,000

__device__ __forceinline__ uint32_t ord_f32(float f) {
    uint32_t u = __float_as_uint(f);
    return (u & 0x80000000u) ? ~u : (u | 0x80000000u);
}
__device__ __forceinline__ uint64_t pack_key(float val, int idx) {
    // max(key) == max value, ties -> smallest idx (numpy argmax semantics)
    return ((uint64_t)ord_f32(val) << 32) | (uint64_t)(0xFFFFFFFFu - (uint32_t)idx);
}
__device__ __forceinline__ int key_idx(uint64_t k) {
    return (int)(0xFFFFFFFFu - (uint32_t)k);
}
__device__ __forceinline__ uint64_t shfl_xor_u64(uint64_t x, int mask) {
    int lo = __shfl_xor((int)(uint32_t)x, mask);
    int hi = __shfl_xor((int)(uint32_t)(x >> 32), mask);
    return ((uint64_t)(uint32_t)hi << 32) | (uint32_t)lo;
}
__device__ __forceinline__ uint64_t umax64(uint64_t a, uint64_t b) { return a > b ? a : b; }
__device__ __forceinline__ float sigmoidf_(float x) { return 1.0f / (1.0f + expf(-x)); }

// pin a genuinely wave-uniform pointer into SGPRs so broadcast loads can scalarize
__device__ __forceinline__ const float* uniform_ptr(const float* p) {
    uintptr_t a = (uintptr_t)p;
    uint32_t lo = (uint32_t)__builtin_amdgcn_readfirstlane((int)(uint32_t)a);
    uint32_t hi = (uint32_t)__builtin_amdgcn_readfirstlane((int)(uint32_t)(a >> 32));
    return (const float*)(((uintptr_t)hi << 32) | lo);
}

// ---------------- W_out transpose: [V][H] -> [H][V] ----------------
__global__ __launch_bounds__(256)
void transpose_kernel(const float* __restrict__ src, float* __restrict__ dst) {
    __shared__ float tile[32][33];
    int vt = blockIdx.x * 32;                 // 0..999
    int kt = blockIdx.y * 32;                 // 0..31
    int tx = threadIdx.x & 31, ty = threadIdx.x >> 5;  // ty 0..7
#pragma unroll
    for (int i = 0; i < 32; i += 8)
        tile[ty + i][tx] = src[(size_t)(vt + ty + i) * H + kt + tx];
    __syncthreads();
#pragma unroll
    for (int i = 0; i < 32; i += 8)
        dst[(size_t)(kt + ty + i) * V + vt + tx] = tile[tx][ty + i];
}

// ---------------- GRU step (float2-vectorized k-loop) ----------------
// Structure identical to the passing version; only the dot-product loop now
// reads 8 B/lane (8 iters) instead of 4 B/lane (16 iters): halves load-issue
// count and the latency chain. VGPR stays ~50 -> 8 waves/SIMD preserved.
__global__ __launch_bounds__(1024)
void gru_kernel(const float* __restrict__ h_prev,    // [B][H]
                const float* __restrict__ emb,       // [V][H]
                const float* __restrict__ W_ih,      // [3H][H]
                const float* __restrict__ W_hh,      // [3H][H]
                const float* __restrict__ b_ih,      // [3H]
                const float* __restrict__ b_hh,      // [3H]
                const uint64_t* __restrict__ amax,   // [B][NPART]
                int use_tok,                         // 0 -> tok = SOS(0)
                float* __restrict__ h_new,           // [B][H]
                float* __restrict__ h_newT)          // [H][B]
{
    int j = blockIdx.x;
    int wave = threadIdx.x >> 6;
    int lane = threadIdx.x & 63;
    int b0 = wave * 2, b1 = wave * 2 + 1;

    int tok0 = 0, tok1 = 0;
    if (use_tok) {
        uint64_t k0 = 0, k1 = 0;
        for (int i = lane; i < NPART; i += 64) {
            k0 = umax64(k0, amax[b0 * NPART + i]);
            k1 = umax64(k1, amax[b1 * NPART + i]);
        }
#pragma unroll
        for (int d = 32; d; d >>= 1) {
            k0 = umax64(k0, shfl_xor_u64(k0, d));
            k1 = umax64(k1, shfl_xor_u64(k1, d));
        }
        tok0 = key_idx(k0);
        tok1 = key_idx(k1);
    }

    const float2* x0_2  = (const float2*)(emb + (size_t)tok0 * H);
    const float2* x1_2  = (const float2*)(emb + (size_t)tok1 * H);
    const float* hp0 = h_prev + (size_t)b0 * H;
    const float* hp1 = h_prev + (size_t)b1 * H;
    const float2* hp0_2 = (const float2*)hp0;
    const float2* hp1_2 = (const float2*)hp1;
    const float* wr = W_ih + (size_t)j * H;
    const float2* wr2 = (const float2*)wr;
    const float2* wz2 = (const float2*)(wr + (size_t)H * H);
    const float2* wn2 = (const float2*)(wr + (size_t)2 * H * H);
    const float* ur = W_hh + (size_t)j * H;
    const float2* ur2 = (const float2*)ur;
    const float2* uz2 = (const float2*)(ur + (size_t)H * H);
    const float2* un2 = (const float2*)(ur + (size_t)2 * H * H);

    float a[12];
#pragma unroll
    for (int i = 0; i < 12; ++i) a[i] = 0.f;

#pragma unroll 1
    for (int i = 0; i < 8; ++i) {            // float2 index f covers k = 2f, 2f+1
        int f = lane + i * 64;               // 0..511
        float2 xv0 = x0_2[f], xv1 = x1_2[f];
        float2 hv0 = hp0_2[f], hv1 = hp1_2[f];
        float2 w1 = wr2[f], w2 = wz2[f], w3 = wn2[f];
        float2 u1 = ur2[f], u2 = uz2[f], u3 = un2[f];
        xv0.x = fmaxf(xv0.x, 0.f); xv0.y = fmaxf(xv0.y, 0.f);
        xv1.x = fmaxf(xv1.x, 0.f); xv1.y = fmaxf(xv1.y, 0.f);
        a[0]  = fmaf(w1.x, xv0.x, fmaf(w1.y, xv0.y, a[0]));
        a[1]  = fmaf(w2.x, xv0.x, fmaf(w2.y, xv0.y, a[1]));
        a[2]  = fmaf(w3.x, xv0.x, fmaf(w3.y, xv0.y, a[2]));
        a[3]  = fmaf(u1.x, hv0.x, fmaf(u1.y, hv0.y, a[3]));
        a[4]  = fmaf(u2.x, hv0.x, fmaf(u2.y, hv0.y, a[4]));
        a[5]  = fmaf(u3.x, hv0.x, fmaf(u3.y, hv0.y, a[5]));
        a[6]  = fmaf(w1.x, xv1.x, fmaf(w1.y, xv1.y, a[6]));
        a[7]  = fmaf(w2.x, xv1.x, fmaf(w2.y, xv1.y, a[7]));
        a[8]  = fmaf(w3.x, xv1.x, fmaf(w3.y, xv1.y, a[8]));
        a[9]  = fmaf(u1.x, hv1.x, fmaf(u1.y, hv1.y, a[9]));
        a[10] = fmaf(u2.x, hv1.x, fmaf(u2.y, hv1.y, a[10]));
        a[11] = fmaf(u3.x, hv1.x, fmaf(u3.y, hv1.y, a[11]));
    }
#pragma unroll
    for (int i = 0; i < 12; ++i) {
#pragma unroll
        for (int d = 32; d; d >>= 1) a[i] += __shfl_xor(a[i], d);
    }

    if (lane == 0) {
        float bir = b_ih[j], biz = b_ih[j + H], bin = b_ih[j + 2 * H];
        float bhr = b_hh[j], bhz = b_hh[j + H], bhn = b_hh[j + 2 * H];
        {
            float r = sigmoidf_((a[0] + bir) + (a[3] + bhr));
            float z = sigmoidf_((a[1] + biz) + (a[4] + bhz));
            float n = tanhf((a[2] + bin) + r * (a[5] + bhn));
            float o = (1.f - z) * n + z * hp0[j];
            h_new[(size_t)b0 * H + j] = o;
            h_newT[(size_t)j * B + b0] = o;
        }
        {
            float r = sigmoidf_((a[6] + bir) + (a[9] + bhr));
            float z = sigmoidf_((a[7] + biz) + (a[10] + bhz));
            float n = tanhf((a[8] + bin) + r * (a[11] + bhn));
            float o = (1.f - z) * n + z * hp1[j];
            h_new[(size_t)b1 * H + j] = o;
            h_newT[(size_t)j * B + b1] = o;
        }
    }
}

// ---------------- logits main GEMM: fat loads, full-SIMD coverage ----------------
// grid = 500 blocks x 512 thr: bid -> (vt = bid>>1: 128-v tile, kh = bid&1: 512-k half).
// Wave w owns k in [kh*512 + w*64, +64); lane owns a float2 of v (512 B/wave/load).
// acc[32][2] = 64 VGPR -> <=128 total -> 4 waves/SIMD, 2 blocks/CU, all 250 v-tile
// pairs resident -> FMA-issue floor ~13.6 us. kh=0 partial goes straight into out,
// kh=1 into part1; bias+argmax happen in combine_kernel.
// NOTE: the last w-prefetch of (kh=1, wave=7) reads WT row 1024 -> lands in part1
// (in-bounds, value unused). part1 MUST directly follow WT in d_ws.
__global__ __launch_bounds__(512, 4)
void logits_mm_kernel(const float* __restrict__ WT,   // [H][V]
                      const float* __restrict__ hT,   // [H][B]
                      float* __restrict__ out,        // d_out logits region
                      float* __restrict__ part1,      // [B][V] partial for kh=1
                      int t)
{
    const int bid  = blockIdx.x;
    const int vt   = bid >> 1;            // 0..249
    const int kh   = bid & 1;
    const int wave = threadIdx.x >> 6;    // 0..7
    const int lane = threadIdx.x & 63;
    const int k0   = kh * 512 + wave * 64;
    const int v    = vt * 128 + lane * 2;

    const float* wp = WT + (size_t)k0 * V + v;
    const float* hrow = uniform_ptr(hT + (size_t)k0 * B);

    float acc[32][2];
#pragma unroll
    for (int b = 0; b < 32; ++b) { acc[b][0] = 0.f; acc[b][1] = 0.f; }

    float2 wcur = *(const float2*)wp;
    wp += V;

#pragma unroll 1
    for (int k = 0; k < 64; ++k) {
        float2 wnxt = *(const float2*)wp;   // k0+1+k; last reads row k0+64 (guarded)
        wp += V;
        const float4* h4 = (const float4*)hrow;
        hrow += B;
#pragma unroll
        for (int q = 0; q < 8; ++q) {
            float4 hv = h4[q];
            acc[4 * q + 0][0] = fmaf(hv.x, wcur.x, acc[4 * q + 0][0]);
            acc[4 * q + 0][1] = fmaf(hv.x, wcur.y, acc[4 * q + 0][1]);
            acc[4 * q + 1][0] = fmaf(hv.y, wcur.x, acc[4 * q + 1][0]);
            acc[4 * q + 1][1] = fmaf(hv.y, wcur.y, acc[4 * q + 1][1]);
            acc[4 * q + 2][0] = fmaf(hv.z, wcur.x, acc[4 * q + 2][0]);
            acc[4 * q + 2][1] = fmaf(hv.z, wcur.y, acc[4 * q + 2][1]);
            acc[4 * q + 3][0] = fmaf(hv.w, wcur.x, acc[4 * q + 3][0]);
            acc[4 * q + 3][1] = fmaf(hv.w, wcur.y, acc[4 * q + 3][1]);
        }
        wcur = wnxt;
    }

    // cross-wave k-reduction: 2 passes of 16 batches through 64 KB LDS
    __shared__ float red[8][2048];
#pragma unroll
    for (int bg = 0; bg < 2; ++bg) {
#pragma unroll
        for (int bl = 0; bl < 16; ++bl) {
            int bb = bg * 16 + bl;
            *(float2*)&red[wave][bl * 128 + lane * 2] = make_float2(acc[bb][0], acc[bb][1]);
        }
        __syncthreads();
#pragma unroll
        for (int q = 0; q < 4; ++q) {
            int c = threadIdx.x + q * 512;      // 0..2047
            float s = red[0][c];
#pragma unroll
            for (int w = 1; w < 8; ++w) s += red[w][c];
            int bl = c >> 7, vloc = c & 127;
            int b = bg * 16 + bl;
            int vv = vt * 128 + vloc;
            if (kh == 0) out[((size_t)b * T + t) * V + vv] = s;
            else         part1[(size_t)b * V + vv] = s;
        }
        __syncthreads();
    }
}

// ---------------- combine halves + bias + store + argmax partials ----------------
// grid = 500 (one per 64-v tile, preserving NPART=500 for gru's decode), block 512.
// Wave w handles batches [4w, 4w+4); identical epilogue semantics to the old kernel.
__global__ __launch_bounds__(512)
void combine_kernel(float* __restrict__ out,
                    const float* __restrict__ part1,
                    const float* __restrict__ b_out,
                    int t,
                    uint64_t* __restrict__ amax)
{
    const int vt   = blockIdx.x;           // 0..499
    const int wave = threadIdx.x >> 6;
    const int lane = threadIdx.x & 63;
    const int v    = vt * 64 + lane;
    const float bias = b_out[v];
#pragma unroll
    for (int bi = 0; bi < 4; ++bi) {
        int b = wave * 4 + bi;
        size_t o = ((size_t)b * T + t) * V + v;
        float s = out[o] + part1[(size_t)b * V + v] + bias;
        out[o] = s;
        uint64_t key = pack_key(s, v);
#pragma unroll
        for (int d = 32; d; d >>= 1) key = umax64(key, shfl_xor_u64(key, d));
        if (lane == 0) amax[(size_t)b * NPART + vt] = key;
    }
}

// ---------------- final log-softmax over each [b][t] row ----------------
__global__ __launch_bounds__(256)
void logsoftmax_kernel(float* __restrict__ out) {
    size_t row = (size_t)blockIdx.x * V;
    int lane = threadIdx.x & 63, wave = threadIdx.x >> 6;
    __shared__ float red[4];

    float m = -INFINITY;
    for (int v = threadIdx.x; v < V; v += 256) m = fmaxf(m, out[row + v]);
#pragma unroll
    for (int d = 32; d; d >>= 1) m = fmaxf(m, __shfl_xor(m, d));
    if (lane == 0) red[wave] = m;
    __syncthreads();
    float M = fmaxf(fmaxf(red[0], red[1]), fmaxf(red[2], red[3]));
    __syncthreads();

    float s = 0.f;
    for (int v = threadIdx.x; v < V; v += 256) s += expf(out[row + v] - M);
#pragma unroll
    for (int d = 32; d; d >>= 1) s += __shfl_xor(s, d);
    if (lane == 0) red[wave] = s;
    __syncthreads();
    float S = red[0] + red[1] + red[2] + red[3];

    float L = M + logf(S);
    for (int v = threadIdx.x; v < V; v += 256) out[row + v] -= L;
}

// ---------------- copy final hidden state to output tail ----------------
__global__ __launch_bounds__(256)
void copy_h_kernel(const float* __restrict__ h, float* __restrict__ out) {
    int i = blockIdx.x * 256 + threadIdx.x;   // 32768 elements
    out[OUT_LOGITS + i] = h[i];
}

}  // namespace

extern "C" void kernel_launch(void* const* d_in, const int* in_sizes, int n_in,
                              void* d_out, int out_size, void* d_ws, size_t ws_size,
                              hipStream_t stream) {
    // d_in: 0 encoder_outputs (unused), 1 encoder_hidden [1,B,H], 2 emb [V,H],
    //       3 W_ih [3H,H], 4 W_hh [3H,H], 5 b_ih [3H], 6 b_hh [3H],
    //       7 W_out [V,H], 8 b_out [V]
    const float* enc_hidden = (const float*)d_in[1];
    const float* emb   = (const float*)d_in[2];
    const float* W_ih  = (const float*)d_in[3];
    const float* W_hh  = (const float*)d_in[4];
    const float* b_ih  = (const float*)d_in[5];
    const float* b_hh  = (const float*)d_in[6];
    const float* W_out = (const float*)d_in[7];
    const float* b_out = (const float*)d_in[8];
    float* out = (float*)d_out;

    float* ws = (float*)d_ws;
    // ws layout (floats): WT (V*H) | part1 (B*V) | hA | hB | hTA | hTB | amax
    // (part1 must directly follow WT: logits' last w-prefetch overruns WT by 1 row)
    const size_t WT_FLOATS = (size_t)V * H;              // 32,768,000
    float* WT    = ws;
    float* part1 = ws + WT_FLOATS;                       // 1,024,000 floats
    float* hA    = part1 + (size_t)B * V;
    float* hB    = hA + 32768;
    float* hTA   = hB + 32768;
    float* hTB   = hTA + 32768;
    uint64_t* amax = (uint64_t*)(hTB + 32768);           // 32*500*8 B = 128 KB

    transpose_kernel<<<dim3(1000, 32), 256, 0, stream>>>(W_out, WT);

    for (int t = 0; t < T; ++t) {
        const float* hp = (t == 0) ? enc_hidden : ((t & 1) ? hA : hB);
        float* hn  = (t & 1) ? hB : hA;
        float* hnT = (t & 1) ? hTB : hTA;
        gru_kernel<<<H, 1024, 0, stream>>>(hp, emb, W_ih, W_hh, b_ih, b_hh,
                                           amax, t == 0 ? 0 : 1, hn, hnT);
        logits_mm_kernel<<<500, 512, 0, stream>>>(WT, hnT, out, part1, t);
        combine_kernel<<<500, 512, 0, stream>>>(out, part1, b_out, t, amax);
    }

    logsoftmax_kernel<<<B * T, 256, 0, stream>>>(out);
    copy_h_kernel<<<32768 / 256, 256, 0, stream>>>(hB, out);  // t=63 wrote hB
}

// Round 6
// 8413.271 us; speedup vs baseline: 1.2518x; 1.0574x over previous
//
#include <hip/hip_runtime.h>
#include <stdint.h>

namespace {

constexpr int H = 1024;
constexpr int V = 32000;
constexpr int B = 32;
constexpr int T = 64;
constexpr int NPART = V / 128;   // 250 argmax partials per batch row (one per 128-v tile)
constexpr long long OUT_LOGITS = (long long)B * T * V;  // 65,536,000

__device__ __forceinline__ uint32_t ord_f32(float f) {
    uint32_t u = __float_as_uint(f);
    return (u & 0x80000000u) ? ~u : (u | 0x80000000u);
}
__device__ __forceinline__ uint64_t pack_key(float val, int idx) {
    // max(key) == max value, ties -> smallest idx (numpy argmax semantics)
    return ((uint64_t)ord_f32(val) << 32) | (uint64_t)(0xFFFFFFFFu - (uint32_t)idx);
}
__device__ __forceinline__ int key_idx(uint64_t k) {
    return (int)(0xFFFFFFFFu - (uint32_t)k);
}
__device__ __forceinline__ uint64_t shfl_xor_u64(uint64_t x, int mask) {
    int lo = __shfl_xor((int)(uint32_t)x, mask);
    int hi = __shfl_xor((int)(uint32_t)(x >> 32), mask);
    return ((uint64_t)(uint32_t)hi << 32) | (uint32_t)lo;
}
__device__ __forceinline__ uint64_t umax64(uint64_t a, uint64_t b) { return a > b ? a : b; }
__device__ __forceinline__ float sigmoidf_(float x) { return 1.0f / (1.0f + expf(-x)); }

// pin a genuinely wave-uniform pointer into SGPRs so broadcast loads can scalarize
__device__ __forceinline__ const float* uniform_ptr(const float* p) {
    uintptr_t a = (uintptr_t)p;
    uint32_t lo = (uint32_t)__builtin_amdgcn_readfirstlane((int)(uint32_t)a);
    uint32_t hi = (uint32_t)__builtin_amdgcn_readfirstlane((int)(uint32_t)(a >> 32));
    return (const float*)(((uintptr_t)hi << 32) | lo);
}

// ---------------- W_out transpose: [V][H] -> [H][V] ----------------
__global__ __launch_bounds__(256)
void transpose_kernel(const float* __restrict__ src, float* __restrict__ dst) {
    __shared__ float tile[32][33];
    int vt = blockIdx.x * 32;                 // 0..999
    int kt = blockIdx.y * 32;                 // 0..31
    int tx = threadIdx.x & 31, ty = threadIdx.x >> 5;  // ty 0..7
#pragma unroll
    for (int i = 0; i < 32; i += 8)
        tile[ty + i][tx] = src[(size_t)(vt + ty + i) * H + kt + tx];
    __syncthreads();
#pragma unroll
    for (int i = 0; i < 32; i += 8)
        dst[(size_t)(kt + ty + i) * V + vt + tx] = tile[tx][ty + i];
}

// ---------------- GRU step (float2-vectorized k-loop) ----------------
// Unchanged from the 8896-us passing version except NPART (500->250 via constant):
// decode loop reads fewer argmax partials, all other semantics identical.
__global__ __launch_bounds__(1024)
void gru_kernel(const float* __restrict__ h_prev,    // [B][H]
                const float* __restrict__ emb,       // [V][H]
                const float* __restrict__ W_ih,      // [3H][H]
                const float* __restrict__ W_hh,      // [3H][H]
                const float* __restrict__ b_ih,      // [3H]
                const float* __restrict__ b_hh,      // [3H]
                const uint64_t* __restrict__ amax,   // [B][NPART]
                int use_tok,                         // 0 -> tok = SOS(0)
                float* __restrict__ h_new,           // [B][H]
                float* __restrict__ h_newT)          // [H][B]
{
    int j = blockIdx.x;
    int wave = threadIdx.x >> 6;
    int lane = threadIdx.x & 63;
    int b0 = wave * 2, b1 = wave * 2 + 1;

    int tok0 = 0, tok1 = 0;
    if (use_tok) {
        uint64_t k0 = 0, k1 = 0;
        for (int i = lane; i < NPART; i += 64) {
            k0 = umax64(k0, amax[b0 * NPART + i]);
            k1 = umax64(k1, amax[b1 * NPART + i]);
        }
#pragma unroll
        for (int d = 32; d; d >>= 1) {
            k0 = umax64(k0, shfl_xor_u64(k0, d));
            k1 = umax64(k1, shfl_xor_u64(k1, d));
        }
        tok0 = key_idx(k0);
        tok1 = key_idx(k1);
    }

    const float2* x0_2  = (const float2*)(emb + (size_t)tok0 * H);
    const float2* x1_2  = (const float2*)(emb + (size_t)tok1 * H);
    const float* hp0 = h_prev + (size_t)b0 * H;
    const float* hp1 = h_prev + (size_t)b1 * H;
    const float2* hp0_2 = (const float2*)hp0;
    const float2* hp1_2 = (const float2*)hp1;
    const float* wr = W_ih + (size_t)j * H;
    const float2* wr2 = (const float2*)wr;
    const float2* wz2 = (const float2*)(wr + (size_t)H * H);
    const float2* wn2 = (const float2*)(wr + (size_t)2 * H * H);
    const float* ur = W_hh + (size_t)j * H;
    const float2* ur2 = (const float2*)ur;
    const float2* uz2 = (const float2*)(ur + (size_t)H * H);
    const float2* un2 = (const float2*)(ur + (size_t)2 * H * H);

    float a[12];
#pragma unroll
    for (int i = 0; i < 12; ++i) a[i] = 0.f;

#pragma unroll 1
    for (int i = 0; i < 8; ++i) {            // float2 index f covers k = 2f, 2f+1
        int f = lane + i * 64;               // 0..511
        float2 xv0 = x0_2[f], xv1 = x1_2[f];
        float2 hv0 = hp0_2[f], hv1 = hp1_2[f];
        float2 w1 = wr2[f], w2 = wz2[f], w3 = wn2[f];
        float2 u1 = ur2[f], u2 = uz2[f], u3 = un2[f];
        xv0.x = fmaxf(xv0.x, 0.f); xv0.y = fmaxf(xv0.y, 0.f);
        xv1.x = fmaxf(xv1.x, 0.f); xv1.y = fmaxf(xv1.y, 0.f);
        a[0]  = fmaf(w1.x, xv0.x, fmaf(w1.y, xv0.y, a[0]));
        a[1]  = fmaf(w2.x, xv0.x, fmaf(w2.y, xv0.y, a[1]));
        a[2]  = fmaf(w3.x, xv0.x, fmaf(w3.y, xv0.y, a[2]));
        a[3]  = fmaf(u1.x, hv0.x, fmaf(u1.y, hv0.y, a[3]));
        a[4]  = fmaf(u2.x, hv0.x, fmaf(u2.y, hv0.y, a[4]));
        a[5]  = fmaf(u3.x, hv0.x, fmaf(u3.y, hv0.y, a[5]));
        a[6]  = fmaf(w1.x, xv1.x, fmaf(w1.y, xv1.y, a[6]));
        a[7]  = fmaf(w2.x, xv1.x, fmaf(w2.y, xv1.y, a[7]));
        a[8]  = fmaf(w3.x, xv1.x, fmaf(w3.y, xv1.y, a[8]));
        a[9]  = fmaf(u1.x, hv1.x, fmaf(u1.y, hv1.y, a[9]));
        a[10] = fmaf(u2.x, hv1.x, fmaf(u2.y, hv1.y, a[10]));
        a[11] = fmaf(u3.x, hv1.x, fmaf(u3.y, hv1.y, a[11]));
    }
#pragma unroll
    for (int i = 0; i < 12; ++i) {
#pragma unroll
        for (int d = 32; d; d >>= 1) a[i] += __shfl_xor(a[i], d);
    }

    if (lane == 0) {
        float bir = b_ih[j], biz = b_ih[j + H], bin = b_ih[j + 2 * H];
        float bhr = b_hh[j], bhz = b_hh[j + H], bhn = b_hh[j + 2 * H];
        {
            float r = sigmoidf_((a[0] + bir) + (a[3] + bhr));
            float z = sigmoidf_((a[1] + biz) + (a[4] + bhz));
            float n = tanhf((a[2] + bin) + r * (a[5] + bhn));
            float o = (1.f - z) * n + z * hp0[j];
            h_new[(size_t)b0 * H + j] = o;
            h_newT[(size_t)j * B + b0] = o;
        }
        {
            float r = sigmoidf_((a[6] + bir) + (a[9] + bhr));
            float z = sigmoidf_((a[7] + biz) + (a[10] + bhz));
            float n = tanhf((a[8] + bin) + r * (a[11] + bhn));
            float o = (1.f - z) * n + z * hp1[j];
            h_new[(size_t)b1 * H + j] = o;
            h_newT[(size_t)j * B + b1] = o;
        }
    }
}

// ---------------- fused logits: full-K blocks, depth-4 W-prefetch ring ----------------
// grid = 250 (one per 128-v tile), block = 1024 = 16 waves. Wave w owns k-chunk
// [w*64, +64); lane owns a float2 of v. Depth-4 register ring on the W stream:
// load issued at step k is consumed at step k+4 -> 4 x 512 B in flight per wave,
// 8 KB/SIMD at 4 waves/SIMD -> Little's-law capacity ~19 TB/s (vs 1-deep ~2 TB/s,
// the round-5 bottleneck). acc[32][2]=64 VGPR; __launch_bounds__(1024,4) caps at
// 128 VGPR -> 16 waves/CU. Epilogue fuses bias + store + argmax partials (no
// combine kernel, no part1).
// NOTE: the ring's last prefetches read <=4 rows past WT (512,000 B) -> land in
// the h-scratch buffers that MUST directly follow WT in d_ws (512 KB, in-bounds,
// values unused).
__global__ __launch_bounds__(1024, 4)
void logits_full_kernel(const float* __restrict__ WT,   // [H][V]
                        const float* __restrict__ hT,   // [H][B]
                        const float* __restrict__ b_out,
                        float* __restrict__ out,        // d_out logits region
                        int t,
                        uint64_t* __restrict__ amax)    // [B][NPART]
{
    const int vt   = blockIdx.x;          // 0..249
    const int wave = threadIdx.x >> 6;    // 0..15 = k-chunk
    const int lane = threadIdx.x & 63;
    const int k0   = wave * 64;
    const int v    = vt * 128 + lane * 2;

    const float* wp = WT + (size_t)k0 * V + v;
    const float* hrow = uniform_ptr(hT + (size_t)k0 * B);

    float acc[32][2];
#pragma unroll
    for (int b = 0; b < 32; ++b) { acc[b][0] = 0.f; acc[b][1] = 0.f; }

    // prologue: fill the 4-deep ring (rows k0 .. k0+3)
    float2 w0 = *(const float2*)wp; wp += V;
    float2 w1 = *(const float2*)wp; wp += V;
    float2 w2 = *(const float2*)wp; wp += V;
    float2 w3 = *(const float2*)wp; wp += V;

    // one ring step: consume wreg (row k), issue load of row k+4 into wreg.
    // All register indices static (hand-rotated ring; no runtime-indexed arrays).
    auto wstep = [&](float2& wreg) {
        float2 wnxt = *(const float2*)wp;   // row k+4 (may overrun WT by <=4 rows)
        wp += V;
        const float4* h4 = (const float4*)hrow;
        hrow += B;
#pragma unroll
        for (int q = 0; q < 8; ++q) {
            float4 hv = h4[q];
            acc[4 * q + 0][0] = fmaf(hv.x, wreg.x, acc[4 * q + 0][0]);
            acc[4 * q + 0][1] = fmaf(hv.x, wreg.y, acc[4 * q + 0][1]);
            acc[4 * q + 1][0] = fmaf(hv.y, wreg.x, acc[4 * q + 1][0]);
            acc[4 * q + 1][1] = fmaf(hv.y, wreg.y, acc[4 * q + 1][1]);
            acc[4 * q + 2][0] = fmaf(hv.z, wreg.x, acc[4 * q + 2][0]);
            acc[4 * q + 2][1] = fmaf(hv.z, wreg.y, acc[4 * q + 2][1]);
            acc[4 * q + 3][0] = fmaf(hv.w, wreg.x, acc[4 * q + 3][0]);
            acc[4 * q + 3][1] = fmaf(hv.w, wreg.y, acc[4 * q + 3][1]);
        }
        wreg = wnxt;
    };

#pragma unroll 1
    for (int k = 0; k < 64; k += 4) {
        wstep(w0);
        wstep(w1);
        wstep(w2);
        wstep(w3);
    }

    // cross-wave k-reduction + fused epilogue: 4 passes of 8 batches through 64 KB LDS
    __shared__ float red[16][1024];
#pragma unroll
    for (int bg = 0; bg < 4; ++bg) {
#pragma unroll
        for (int bl = 0; bl < 8; ++bl) {
            int bb = bg * 8 + bl;
            *(float2*)&red[wave][bl * 128 + lane * 2] = make_float2(acc[bb][0], acc[bb][1]);
        }
        __syncthreads();
        if (wave < 8) {
            int b = bg * 8 + wave;
            float s0 = 0.f, s1 = 0.f;
#pragma unroll
            for (int kw = 0; kw < 16; ++kw) {
                float2 r = *(const float2*)&red[kw][wave * 128 + lane * 2];
                s0 += r.x; s1 += r.y;
            }
            float2 bias = *(const float2*)&b_out[v];
            s0 += bias.x; s1 += bias.y;
            *(float2*)&out[((size_t)b * T + t) * V + v] = make_float2(s0, s1);

            uint64_t key = umax64(pack_key(s0, v), pack_key(s1, v + 1));
#pragma unroll
            for (int d = 32; d; d >>= 1) key = umax64(key, shfl_xor_u64(key, d));
            if (lane == 0) amax[(size_t)b * NPART + vt] = key;
        }
        __syncthreads();
    }
}

// ---------------- final log-softmax over each [b][t] row ----------------
__global__ __launch_bounds__(256)
void logsoftmax_kernel(float* __restrict__ out) {
    size_t row = (size_t)blockIdx.x * V;
    int lane = threadIdx.x & 63, wave = threadIdx.x >> 6;
    __shared__ float red[4];

    float m = -INFINITY;
    for (int v = threadIdx.x; v < V; v += 256) m = fmaxf(m, out[row + v]);
#pragma unroll
    for (int d = 32; d; d >>= 1) m = fmaxf(m, __shfl_xor(m, d));
    if (lane == 0) red[wave] = m;
    __syncthreads();
    float M = fmaxf(fmaxf(red[0], red[1]), fmaxf(red[2], red[3]));
    __syncthreads();

    float s = 0.f;
    for (int v = threadIdx.x; v < V; v += 256) s += expf(out[row + v] - M);
#pragma unroll
    for (int d = 32; d; d >>= 1) s += __shfl_xor(s, d);
    if (lane == 0) red[wave] = s;
    __syncthreads();
    float S = red[0] + red[1] + red[2] + red[3];

    float L = M + logf(S);
    for (int v = threadIdx.x; v < V; v += 256) out[row + v] -= L;
}

// ---------------- copy final hidden state to output tail ----------------
__global__ __launch_bounds__(256)
void copy_h_kernel(const float* __restrict__ h, float* __restrict__ out) {
    int i = blockIdx.x * 256 + threadIdx.x;   // 32768 elements
    out[OUT_LOGITS + i] = h[i];
}

}  // namespace

extern "C" void kernel_launch(void* const* d_in, const int* in_sizes, int n_in,
                              void* d_out, int out_size, void* d_ws, size_t ws_size,
                              hipStream_t stream) {
    // d_in: 0 encoder_outputs (unused), 1 encoder_hidden [1,B,H], 2 emb [V,H],
    //       3 W_ih [3H,H], 4 W_hh [3H,H], 5 b_ih [3H], 6 b_hh [3H],
    //       7 W_out [V,H], 8 b_out [V]
    const float* enc_hidden = (const float*)d_in[1];
    const float* emb   = (const float*)d_in[2];
    const float* W_ih  = (const float*)d_in[3];
    const float* W_hh  = (const float*)d_in[4];
    const float* b_ih  = (const float*)d_in[5];
    const float* b_hh  = (const float*)d_in[6];
    const float* W_out = (const float*)d_in[7];
    const float* b_out = (const float*)d_in[8];
    float* out = (float*)d_out;

    float* ws = (float*)d_ws;
    // ws layout (floats): WT (V*H) | hA | hB | hTA | hTB | amax (u64 [B][NPART])
    // (hA..hTB = 512 KB MUST directly follow WT: logits' depth-4 ring prefetch
    //  overruns WT by up to 4 rows = 512,000 B; reads land here, values unused)
    const size_t WT_FLOATS = (size_t)V * H;              // 32,768,000
    float* WT    = ws;
    float* hA    = ws + WT_FLOATS;
    float* hB    = hA + 32768;
    float* hTA   = hB + 32768;
    float* hTB   = hTA + 32768;
    uint64_t* amax = (uint64_t*)(hTB + 32768);           // 32*250*8 B = 64 KB

    transpose_kernel<<<dim3(1000, 32), 256, 0, stream>>>(W_out, WT);

    for (int t = 0; t < T; ++t) {
        const float* hp = (t == 0) ? enc_hidden : ((t & 1) ? hA : hB);
        float* hn  = (t & 1) ? hB : hA;
        float* hnT = (t & 1) ? hTB : hTA;
        gru_kernel<<<H, 1024, 0, stream>>>(hp, emb, W_ih, W_hh, b_ih, b_hh,
                                           amax, t == 0 ? 0 : 1, hn, hnT);
        logits_full_kernel<<<V / 128, 1024, 0, stream>>>(WT, hnT, b_out, out, t, amax);
    }

    logsoftmax_kernel<<<B * T, 256, 0, stream>>>(out);
    copy_h_kernel<<<32768 / 256, 256, 0, stream>>>(hB, out);  // t=63 wrote hB
}